// Round 7
// baseline (238.867 us; speedup 1.0000x reference)
//
#include <hip/hip_runtime.h>

#define NC 14
#define DIM 96
#define PP (DIM*DIM*DIM)          // 884736 voxels per batch
#define VPT 8                     // voxels per thread
#define VPB (256*VPT)             // 2048 voxels per block
#define BLOCKS_PER_B (PP/VPB)     // 432 blocks per batch

typedef __attribute__((address_space(1))) const void* gas_vp;
typedef __attribute__((address_space(3))) void*       las_vp;

// S/T streamed through the global_load_lds (direct-to-LDS DMA) path instead of
// the plain VMEM-return path, which capped at ~2.7 TB/s delivered in R1-R6.
// Double-buffered LDS per class; labels/masks via plain loads (R6 verbatim).
__global__ __launch_bounds__(256) void bkd_main(
    const float* __restrict__ S, const float* __restrict__ T,
    const int* __restrict__ lab,
    double* __restrict__ gnum, int* __restrict__ gcnt)
{
    __shared__ __align__(16) float bufT[2][VPB];   // 2 x 8 KB
    __shared__ __align__(16) float bufS[2][VPB];   // 2 x 8 KB
    __shared__ float s_num[NC];
    __shared__ int   s_cnt[NC];

    const int tid  = threadIdx.x;
    const int lane = tid & 63;
    const int wv   = tid >> 6;                             // wave 0..3
    const unsigned bq = blockIdx.x;
    const unsigned b  = bq / BLOCKS_PER_B;                 // 0/1, block-uniform
    const int p0 = (int)((bq - b * BLOCKS_PER_B) * VPB);   // block chunk start
    const int p  = p0 + tid * VPT;
    const int d  = p % DIM;                                // multiple of 8
    const int t  = p / DIM;
    const int w  = t % DIM;
    const int h  = t / DIM;

    // ---- labels & masks first (plain loads; consumed before staging begins) ----
    const int lbase = (int)b * PP;
    unsigned mk[VPT];
#pragma unroll
    for (int i = 0; i < VPT; ++i) mk[i] = 0u;

#pragma unroll
    for (int dh = -1; dh <= 1; ++dh) {
        const int hh = h + dh;
        if ((unsigned)hh >= (unsigned)DIM) continue;
#pragma unroll
        for (int dw = -1; dw <= 1; ++dw) {
            const int ww = w + dw;
            if ((unsigned)ww >= (unsigned)DIM) continue;
            const int* rp = lab + lbase + (hh * DIM + ww) * DIM + d;
            const int4 v0 = *(const int4*)rp;
            const int4 v1 = *(const int4*)(rp + 4);
            unsigned lb[VPT + 2];                    // label bits at d-1 .. d+8
            lb[0] = (d > 0)         ? (1u << rp[-1])  : 0u;
            lb[1] = 1u << v0.x;  lb[2] = 1u << v0.y;
            lb[3] = 1u << v0.z;  lb[4] = 1u << v0.w;
            lb[5] = 1u << v1.x;  lb[6] = 1u << v1.y;
            lb[7] = 1u << v1.z;  lb[8] = 1u << v1.w;
            lb[9] = (d < DIM - VPT) ? (1u << rp[VPT]) : 0u;
            if (dh == 0 && dw == 0) {                // center row: exclude own voxel
#pragma unroll
                for (int i = 0; i < VPT; ++i) mk[i] |= lb[i] | lb[i + 2];
            } else {
#pragma unroll
                for (int i = 0; i < VPT; ++i) mk[i] |= lb[i] | lb[i + 1] | lb[i + 2];
            }
        }
    }

    // interior voxel with a single distinct neighbor class contributes nothing
    const bool hwi = (h >= 1 && h <= DIM - 2 && w >= 1 && w <= DIM - 2);
#pragma unroll
    for (int i = 0; i < VPT; ++i) {
        const int dd = d + i;
        const bool din = (dd > 0) && (dd < DIM - 1);
        if (hwi && din && (mk[i] & (mk[i] - 1)) == 0u) mk[i] = 0u;
    }

    // ---- S/T class loop through LDS (global_load_lds, double-buffered) ----
    // wave 0: T[0,1024)  wave 1: T[1024,2048)  wave 2: S[0,1024)  wave 3: S[1024,2048)
    const float* gT = T + (size_t)b * NC * PP + p0 + ((wv & 1) ? 1024 : 0);
    const float* gS = S + (size_t)b * NC * PP + p0 + ((wv & 1) ? 1024 : 0);
    const float* gsrc = (wv < 2) ? gT : gS;

    float ZT[VPT], ZS[VPT], A[VPT];
#pragma unroll
    for (int i = 0; i < VPT; ++i) { ZT[i] = 0.f; ZS[i] = 0.f; A[i] = 0.f; }

#define STAGE(c, bi)                                                          \
    {                                                                         \
        const float* gp = gsrc + (size_t)(c) * PP;                            \
        float* lp = ((wv < 2) ? bufT[bi] : bufS[bi]) + ((wv & 1) ? 1024 : 0); \
        _Pragma("unroll")                                                     \
        for (int seg = 0; seg < 4; ++seg) {                                   \
            __builtin_amdgcn_global_load_lds(                                 \
                (gas_vp)(const void*)(gp + seg * 256 + lane * 4),             \
                (las_vp)(void*)(lp + seg * 256 + lane * 4),                   \
                16, 0, 0);                                                    \
        }                                                                     \
    }

#define CONSUME(bi)                                                           \
    {                                                                         \
        const float4 t0 = *(const float4*)&bufT[bi][tid * VPT];               \
        const float4 t1 = *(const float4*)&bufT[bi][tid * VPT + 4];           \
        const float4 s0 = *(const float4*)&bufS[bi][tid * VPT];               \
        const float4 s1 = *(const float4*)&bufS[bi][tid * VPT + 4];           \
        const float tv[VPT] = {t0.x,t0.y,t0.z,t0.w,t1.x,t1.y,t1.z,t1.w};      \
        const float sv[VPT] = {s0.x,s0.y,s0.z,s0.w,s1.x,s1.y,s1.z,s1.w};      \
        _Pragma("unroll")                                                     \
        for (int i = 0; i < VPT; ++i) {                                       \
            const float u = __expf(tv[i]);                                    \
            ZT[i] += u;                                                       \
            ZS[i] += __expf(sv[i]);                                           \
            A[i]   = fmaf(u, tv[i] - sv[i], A[i]);                            \
        }                                                                     \
    }

    STAGE(0, 0);
    __syncthreads();                 // stage(0) landed
#pragma unroll 1
    for (int c = 0; c < NC; ++c) {
        if (c + 1 < NC) STAGE(c + 1, (c + 1) & 1);   // prefetch into other buffer
        CONSUME(c & 1);                              // overlaps prefetch flight
        __syncthreads();             // stage(c+1) landed; buffer c&1 free for c+2
    }
#undef STAGE
#undef CONSUME

    float kl[VPT];
#pragma unroll
    for (int i = 0; i < VPT; ++i)
        kl[i] = A[i] / ZT[i] + __logf(ZS[i]) - __logf(ZT[i]);

    // ---- per-class accumulate (registers) ----
    float lnum[NC];
    int   lcnt[NC];
#pragma unroll
    for (int k = 0; k < NC; ++k) { lnum[k] = 0.f; lcnt[k] = 0; }
#pragma unroll
    for (int i = 0; i < VPT; ++i) {
        const float kv = kl[i];
        const unsigned mm = mk[i];
#pragma unroll
        for (int k = 0; k < NC; ++k) {
            lnum[k] += (mm & (1u << k)) ? kv : 0.f;
            lcnt[k] += (mm >> k) & 1u;
        }
    }

    // ---- wave (64-lane) shuffle reduction ----
#pragma unroll
    for (int k = 0; k < NC; ++k) {
        float v = lnum[k];
        int   c = lcnt[k];
#pragma unroll
        for (int off = 32; off > 0; off >>= 1) {
            v += __shfl_down(v, off, 64);
            c += __shfl_down(c, off, 64);
        }
        lnum[k] = v; lcnt[k] = c;
    }

    if (tid < NC) { s_num[tid] = 0.f; s_cnt[tid] = 0; }
    __syncthreads();
    if ((tid & 63) == 0) {
#pragma unroll
        for (int k = 0; k < NC; ++k) {
            atomicAdd(&s_num[k], lnum[k]);
            atomicAdd(&s_cnt[k], lcnt[k]);
        }
    }
    __syncthreads();
    if (tid < NC) {
        atomicAdd(&gnum[b * NC + tid], (double)s_num[tid]);
        atomicAdd(&gcnt[b * NC + tid], s_cnt[tid]);
    }
}

__global__ void bkd_final(const double* __restrict__ gnum,
                          const int* __restrict__ gcnt,
                          float* __restrict__ out)
{
    const int i = threadIdx.x;            // one block of 64 threads
    double term = 0.0;
    if (i < 2 * NC) {
        const int c = gcnt[i];
        if (c > 0) term = gnum[i] / ((double)NC * (double)c);
    }
#pragma unroll
    for (int off = 32; off > 0; off >>= 1)
        term += __shfl_down(term, off, 64);
    if (i == 0) out[0] = (float)term;
}

extern "C" void kernel_launch(void* const* d_in, const int* in_sizes, int n_in,
                              void* d_out, int out_size, void* d_ws, size_t ws_size,
                              hipStream_t stream) {
    const float* S  = (const float*)d_in[0];   // preds_S [2,14,96,96,96] f32
    const float* T  = (const float*)d_in[1];   // preds_T [2,14,96,96,96] f32
    const int* lab  = (const int*)d_in[2];     // gt_labels [2,1,96,96,96] int32
    float* out      = (float*)d_out;

    double* gnum = (double*)d_ws;                                   // [2*14]
    int*    gcnt = (int*)((char*)d_ws + 2 * NC * sizeof(double));   // [2*14]

    hipMemsetAsync(d_ws, 0, 2 * NC * (sizeof(double) + sizeof(int)), stream);

    bkd_main<<<2 * BLOCKS_PER_B, 256, 0, stream>>>(S, T, lab, gnum, gcnt);
    bkd_final<<<1, 64, 0, stream>>>(gnum, gcnt, out);
}